// Round 14
// baseline (329.629 us; speedup 1.0000x reference)
//
#include <hip/hip_runtime.h>
#include <hip/hip_bf16.h>

// ---------------------------------------------------------------------------
// Nemotron-H MoE: T=4096 H=1024 E=32 (top-8, grouped 8x4) I=512, SI=2048.
// Round 14: R13 structure (256x128 single-buffered 2-phase, 2 blocks/CU)
// with the routed GEMM cores switched to mfma_f32_32x32x16_f16 (higher
// measured ceiling, half the MFMA issue count). Epilogues use the verified
// 32x32 C/D map: col=lane&31, row=(reg&3)+8*(reg>>2)+4*(lane>>5).
// ---------------------------------------------------------------------------

typedef _Float16 h8 __attribute__((ext_vector_type(8)));
typedef _Float16 h4 __attribute__((ext_vector_type(4)));
typedef float f4 __attribute__((ext_vector_type(4)));
typedef float f16v __attribute__((ext_vector_type(16)));

#define T_TOK 4096
#define HDIM  1024
#define NEXP  32
#define IDIM  512
#define SIDIM 2048
#define TOPK  8
#define MAXTU 224   // routed <=160 + shared 4*16; divisible by 8 (XCD swizzle)
#define MAXTD 160   // divisible by 8

// bijective XCD chunking (m204)
__device__ __forceinline__ int xcd_swz(int orig, int n) {
    int q = n >> 3, r = n & 7;
    int x = orig & 7, idx = orig >> 3;
    return (x < r ? x * (q + 1) : r * (q + 1) + (x - r) * q) + idx;
}

// async global->LDS, 16B per lane; LDS dest = wave-uniform base + lane*16
__device__ __forceinline__ void gload16(const void* g, void* l) {
    __builtin_amdgcn_global_load_lds(
        (const __attribute__((address_space(1))) void*)g,
        (__attribute__((address_space(3))) void*)l, 16, 0, 0);
}

// ------------------------------------------------ merged fp32->fp16 conversions
__global__ __launch_bounds__(256) void cvt_all_kernel(
    const float* __restrict__ sA, _Float16* __restrict__ dA, int nA,
    const float* __restrict__ sB, _Float16* __restrict__ dB, int nB,
    const float* __restrict__ sC, _Float16* __restrict__ dC, int nC,
    const float* __restrict__ sD, _Float16* __restrict__ dD, int nD,
    const float* __restrict__ sE, _Float16* __restrict__ dE, int nE) {
    const int total = nA + nB + nC + nD + nE;
    for (int gi = blockIdx.x * 256 + threadIdx.x; gi < total; gi += gridDim.x * 256) {
        const float* s; _Float16* d; int i = gi;
        if (i < nA) { s = sA; d = dA; }
        else { i -= nA;
        if (i < nB) { s = sB; d = dB; }
        else { i -= nB;
        if (i < nC) { s = sC; d = dC; }
        else { i -= nC;
        if (i < nD) { s = sD; d = dD; }
        else { i -= nD; s = sE; d = dE; } } } }
        float4 v = reinterpret_cast<const float4*>(s)[i];
        h4 h; h[0] = (_Float16)v.x; h[1] = (_Float16)v.y; h[2] = (_Float16)v.z; h[3] = (_Float16)v.w;
        reinterpret_cast<h4*>(d)[i] = h;
    }
}

// ------------------------------------------------ router: fp64 logits + select
__global__ __launch_bounds__(256) void logits_select_kernel(
    const float* __restrict__ x, const float* __restrict__ gw,
    const float* __restrict__ bias, int* __restrict__ topk_ids,
    float* __restrict__ topk_w) {
    const int t0  = blockIdx.x * 16;
    const int tid = threadIdx.x;
    __shared__ double xS[16][66];
    __shared__ double gS[32][65];
    __shared__ double sS[16][33];
    __shared__ double sfcS[16][33];
    const int e  = tid & 31;
    const int tg = tid >> 5;
    const int tA = tg * 2, tB = tg * 2 + 1;
    double acc0 = 0.0, acc1 = 0.0;

    for (int kc = 0; kc < HDIM; kc += 64) {
        {
            int r = tid >> 4, c0 = (tid & 15) * 4;
            float4 v = *reinterpret_cast<const float4*>(x + (size_t)(t0 + r) * HDIM + kc + c0);
            xS[r][c0]     = (double)v.x;
            xS[r][c0 + 1] = (double)v.y;
            xS[r][c0 + 2] = (double)v.z;
            xS[r][c0 + 3] = (double)v.w;
        }
        {
            int r = tid >> 3, c0 = (tid & 7) * 8;
            const float* gp = gw + (size_t)r * HDIM + kc + c0;
            float4 v0 = *reinterpret_cast<const float4*>(gp);
            float4 v1 = *reinterpret_cast<const float4*>(gp + 4);
            gS[r][c0]     = (double)v0.x;
            gS[r][c0 + 1] = (double)v0.y;
            gS[r][c0 + 2] = (double)v0.z;
            gS[r][c0 + 3] = (double)v0.w;
            gS[r][c0 + 4] = (double)v1.x;
            gS[r][c0 + 5] = (double)v1.y;
            gS[r][c0 + 6] = (double)v1.z;
            gS[r][c0 + 7] = (double)v1.w;
        }
        __syncthreads();
#pragma unroll
        for (int k = 0; k < 64; ++k) {
            double g = gS[e][k];
            acc0 = fma(g, xS[tA][k], acc0);
            acc1 = fma(g, xS[tB][k], acc1);
        }
        __syncthreads();
    }
    {
        double s0 = 1.0 / (1.0 + exp(-acc0));
        double s1 = 1.0 / (1.0 + exp(-acc1));
        double b = (double)bias[e];
        sS[tA][e] = s0;  sfcS[tA][e] = s0 + b;
        sS[tB][e] = s1;  sfcS[tB][e] = s1 + b;
    }
    __syncthreads();

    if (tid < 16) {
        const int t = t0 + tid;
        double gsc[8];
        for (int g = 0; g < 8; ++g) {
            double m1 = -1e300, m2 = -1e300;
            for (int j = 0; j < 4; ++j) {
                double v = sfcS[tid][g * 4 + j];
                if (v > m1) { m2 = m1; m1 = v; } else if (v > m2) { m2 = v; }
            }
            gsc[g] = m1 + m2;
        }
        bool gsel[8] = {};
        for (int r = 0; r < 4; ++r) {
            int best = 0; double bv = -1e300;
            for (int g = 0; g < 8; ++g)
                if (!gsel[g] && gsc[g] > bv) { bv = gsc[g]; best = g; }
            gsel[best] = true;
        }
        bool esel[32];
        for (int i2 = 0; i2 < 32; ++i2) esel[i2] = false;
        int ids[8]; double wsum = 0.0;
        for (int r = 0; r < 8; ++r) {
            int best = 0; double bv = -1e300;
            for (int e2 = 0; e2 < 32; ++e2)
                if (gsel[e2 >> 2] && !esel[e2] && sfcS[tid][e2] > bv) { bv = sfcS[tid][e2]; best = e2; }
            esel[best] = true;
            ids[r] = best;
            wsum += sS[tid][best];
        }
        for (int r = 0; r < 8; ++r) {
            topk_ids[t * TOPK + r] = ids[r];
            topk_w[t * TOPK + r] = (float)(sS[tid][ids[r]] / wsum * 2.5);
        }
    }
}

// --------------------------- build lists + scan (last-block does the scan)
__global__ void build_scan_kernel(const int* __restrict__ ids, const float* __restrict__ w,
                                  int* __restrict__ tok_list, float* __restrict__ wt_list,
                                  int* __restrict__ dest_list, int* __restrict__ counts,
                                  int* __restrict__ offsets, int* __restrict__ tmapU,
                                  int* __restrict__ tmapD, int* __restrict__ done) {
    const int e = blockIdx.x;
    const int lane = threadIdx.x;  // block of 64
    int base = 0;
    for (int t0 = 0; t0 < T_TOK; t0 += 64) {
        int t = t0 + lane;
        int found = -1;
#pragma unroll
        for (int k = 0; k < TOPK; ++k)
            if (ids[t * TOPK + k] == e) found = k;
        unsigned long long mask = __ballot(found >= 0);
        if (found >= 0) {
            int pos = base + __popcll(mask & ((1ull << lane) - 1ull));
            tok_list[e * T_TOK + pos]  = t;
            wt_list[e * T_TOK + pos]   = w[t * TOPK + found];
            dest_list[e * T_TOK + pos] = t * TOPK + found;
        }
        base += __popcll(mask);
    }
    if (lane == 0) counts[e] = base;
    __threadfence();
    if (lane == 0 && atomicAdd(done, 1) == NEXP - 1) {
        int run = 0, ntu = 0, ntd = 0;
        for (int ee = 0; ee < NEXP; ++ee) {
            offsets[ee] = run;
            int c = counts[ee];
            for (int m0 = 0; m0 < c; m0 += 256) {
                tmapU[1 + 2 * ntu] = ee; tmapU[2 + 2 * ntu] = m0; ++ntu;
                tmapD[1 + 2 * ntd] = ee; tmapD[2 + 2 * ntd] = m0; ++ntd;
            }
            run += c;
        }
        offsets[NEXP] = run;
        for (int c = 0; c < 4; ++c)
            for (int m0 = 0; m0 < T_TOK; m0 += 256) {
                tmapU[1 + 2 * ntu] = NEXP + c; tmapU[2 + 2 * ntu] = m0; ++ntu;
            }
        tmapU[0] = ntu;
        tmapD[0] = ntd;
    }
}

// ---------------------------------------------------------------------------
// gemm2p (32x32 variant): 256x128 tile, BK=64, 256 threads (4 waves = 2M x 2N;
// per-wave output 128x64 = 4 Mfrags x 2 Nfrags of 32x32, acc = 8 x f32x16).
// Single-buffered LDS (48KB) -> 2 blocks/CU (reg-bound ~240/wave).
// Per K-tile: {stage 12 gload16; __syncthreads; 4 K-slices x {6 ds_read_b128
// + 8 mfma_32x32x16}; __syncthreads}. Same XOR chunk swizzle: A/B frag rows
// step by 32 (par = row&7 invariant), chunk idx = 2*slice + (lane>>5).
// A-frag (extrapolated from verified 32x32x8): row=lane&31, k=8*(lane>>5)+0..7.
// ---------------------------------------------------------------------------
__device__ __forceinline__ void gemm2p(const _Float16* const (&aP)[8],
                                       const _Float16* const (&bP)[4],
                                       const int nt, f16v (&acc)[4][2]) {
    __shared__ __attribute__((aligned(16))) _Float16 As[256 * 64];
    __shared__ __attribute__((aligned(16))) _Float16 Bs[128 * 64];
    const int tid = threadIdx.x;
    const int w = tid >> 6, lane = tid & 63;
    const int wr = w >> 1, wc = w & 1;
    const int row32 = lane & 31, hi = lane >> 5;
    const int ldsw = w * 512;                     // wave's 8-row staging chunk
    const int arow = wr * 128 + row32;            // + m*32
    const int brow = wc * 64 + row32;             // + n*32
    const int apar = arow & 7, bpar = brow & 7;   // invariant under +m*32/+n*32

    for (int t = 0; t < nt; ++t) {
        const int ko = t * 64;
        // stage tile t (single buffer): A 8 sweeps of 32 rows, B 4 sweeps
#pragma unroll
        for (int s = 0; s < 8; ++s)
            gload16(aP[s] + ko, &As[s * 2048 + ldsw]);
#pragma unroll
        for (int s = 0; s < 4; ++s)
            gload16(bP[s] + ko, &Bs[s * 2048 + ldsw]);
        __syncthreads();   // compiler drains vmcnt+lgkm; co-block computes

#pragma unroll
        for (int s = 0; s < 4; ++s) {
            const int ca = (((2 * s + hi) ^ apar)) << 3;   // swizzled chunk (halfs)
            const int cb = (((2 * s + hi) ^ bpar)) << 3;
            h8 bf[2], af[4];
#pragma unroll
            for (int n = 0; n < 2; ++n)
                bf[n] = *reinterpret_cast<const h8*>(&Bs[(brow + n * 32) * 64 + cb]);
#pragma unroll
            for (int m = 0; m < 4; ++m)
                af[m] = *reinterpret_cast<const h8*>(&As[(arow + m * 32) * 64 + ca]);
            __builtin_amdgcn_s_setprio(1);
#pragma unroll
            for (int m = 0; m < 4; ++m)
#pragma unroll
                for (int n = 0; n < 2; ++n)
                    acc[m][n] = __builtin_amdgcn_mfma_f32_32x32x16_f16(af[m], bf[n], acc[m][n], 0, 0, 0);
            __builtin_amdgcn_s_setprio(0);
        }
        __syncthreads();   // all reads retired before next stage overwrites
    }
}

// ------------------------------ unified up: routed relu^2*g and shared relu^2
__global__ __launch_bounds__(256, 2) void up_kernel(
    const _Float16* __restrict__ xh, const _Float16* __restrict__ whup,
    const _Float16* __restrict__ shupW,
    const int* __restrict__ tok_list, const float* __restrict__ wt_list,
    const int* __restrict__ counts, const int* __restrict__ offsets,
    const int* __restrict__ tmap,
    _Float16* __restrict__ hbuf, _Float16* __restrict__ shb) {
    const int ntile = tmap[0];
    int ti = blockIdx.x;
    if (ti >= ntile) return;
    ti = xcd_swz(ti, ntile);
    const int e  = tmap[1 + 2 * ti];
    const int m0 = tmap[2 + 2 * ti];
    const int n0 = blockIdx.y * 128;
    const bool routed = e < NEXP;
    const int cnt = routed ? counts[e] : T_TOK;

    __shared__ int   tokS[256];
    __shared__ float wS[256];
    const int tid = threadIdx.x;
    {
        int row = m0 + tid;
        int cr = row < cnt ? row : cnt - 1;
        if (routed) {
            tokS[tid] = tok_list[e * T_TOK + cr];
            wS[tid]   = row < cnt ? wt_list[e * T_TOK + row] : 0.f;
        } else {
            tokS[tid] = cr;
            wS[tid]   = 1.f;
        }
    }
    __syncthreads();

    const int w = tid >> 6, lane = tid & 63;
    const int swz = ((lane & 7) ^ (lane >> 3)) << 3;
    const int rr = w * 8 + (lane >> 3);    // 0..31: row within each 32-row sweep
    const _Float16* bbase = routed ? (whup + (size_t)e * IDIM * HDIM)
                                   : (shupW + (size_t)(e - NEXP) * 512 * HDIM);
    const _Float16* aP[8]; const _Float16* bP[4];
#pragma unroll
    for (int s = 0; s < 8; ++s)
        aP[s] = xh + (size_t)tokS[s * 32 + rr] * HDIM + swz;
#pragma unroll
    for (int s = 0; s < 4; ++s)
        bP[s] = bbase + (size_t)(n0 + s * 32 + rr) * HDIM + swz;

    f16v acc[4][2] = {};
    gemm2p(aP, bP, HDIM / 64, acc);

    const int wr = w >> 1, wc = w & 1;
    const int col = lane & 31, hi = lane >> 5;
    _Float16* obase; size_t ostr;
    if (routed) { obase = hbuf + (size_t)(offsets[e] + m0) * IDIM + n0; ostr = IDIM; }
    else        { obase = shb + (size_t)m0 * SIDIM + (size_t)(e - NEXP) * 512 + n0; ostr = SIDIM; }
#pragma unroll
    for (int m = 0; m < 4; ++m)
#pragma unroll
    for (int r = 0; r < 16; ++r) {
        int orow = wr * 128 + m * 32 + (r & 3) + 8 * (r >> 2) + 4 * hi;
        if (m0 + orow < cnt) {
            float g = wS[orow];
#pragma unroll
            for (int n = 0; n < 2; ++n) {
                float v = fmaxf(acc[m][n][r], 0.f);
                obase[(size_t)orow * ostr + wc * 64 + n * 32 + col] = (_Float16)(v * v * g);
            }
        }
    }
}

// ------------------------------------------------ routed down (2-phase core)
template<bool SLOT>
__global__ __launch_bounds__(256, 2) void down_routed_kernel(
    const _Float16* __restrict__ hbuf, const _Float16* __restrict__ whdown,
    const int* __restrict__ dest_list, const int* __restrict__ counts,
    const int* __restrict__ offsets, const int* __restrict__ tmap,
    _Float16* __restrict__ slotout, float* __restrict__ out) {
    const int ntile = tmap[0];
    int ti = blockIdx.x;
    if (ti >= ntile) return;
    ti = xcd_swz(ti, ntile);
    const int e   = tmap[1 + 2 * ti];
    const int m0  = tmap[2 + 2 * ti];
    const int cnt = counts[e];
    const int n0   = blockIdx.y * 128;
    const int eoff = offsets[e];

    __shared__ int dS[256];
    const int tid = threadIdx.x;
    {
        int row = m0 + tid;
        dS[tid] = dest_list[e * T_TOK + (row < cnt ? row : cnt - 1)];
    }
    __syncthreads();

    const int w = tid >> 6, lane = tid & 63;
    const int swz = ((lane & 7) ^ (lane >> 3)) << 3;
    const int rr = w * 8 + (lane >> 3);
    const _Float16* aP[8]; const _Float16* bP[4];
#pragma unroll
    for (int s = 0; s < 8; ++s) {
        int row = m0 + s * 32 + rr;
        int cr  = row < cnt ? row : cnt - 1;
        aP[s] = hbuf + (size_t)(eoff + cr) * IDIM + swz;
    }
#pragma unroll
    for (int s = 0; s < 4; ++s)
        bP[s] = whdown + ((size_t)e * HDIM + n0 + s * 32 + rr) * IDIM + swz;

    f16v acc[4][2] = {};
    gemm2p(aP, bP, IDIM / 64, acc);

    const int wr = w >> 1, wc = w & 1;
    const int col = lane & 31, hi = lane >> 5;
#pragma unroll
    for (int m = 0; m < 4; ++m)
#pragma unroll
    for (int r = 0; r < 16; ++r) {
        int orow = wr * 128 + m * 32 + (r & 3) + 8 * (r >> 2) + 4 * hi;
        if (m0 + orow < cnt) {
            int d = dS[orow];
            if (SLOT) {
                size_t rb = (size_t)d * HDIM + n0;
#pragma unroll
                for (int n = 0; n < 2; ++n)
                    slotout[rb + wc * 64 + n * 32 + col] = (_Float16)acc[m][n][r];
            } else {
                size_t rb = (size_t)(d >> 3) * HDIM + n0;
#pragma unroll
                for (int n = 0; n < 2; ++n)
                    atomicAdd(&out[rb + wc * 64 + n * 32 + col], acc[m][n][r]);
            }
        }
    }
}

// ---------------------------------------------------------------------------
// 128x128 2-phase GEMM (down_shared: 256-block grid + fused combine).
// (unchanged, 16x16 MFMA, known-good)
// ---------------------------------------------------------------------------
template<int K>
__device__ __forceinline__ void gemm128(const _Float16* const (&aSrc)[4],
                                        const _Float16* const (&bSrc)[4],
                                        f4 (&acc)[4][4]) {
    __shared__ __attribute__((aligned(16))) _Float16 As[128 * 64];
    __shared__ __attribute__((aligned(16))) _Float16 Bs[128 * 64];
    const int tid  = threadIdx.x;
    const int w    = tid >> 6, lane = tid & 63;
    const int wm   = (w & 1) * 64, wn = (w >> 1) * 64;
    const int ra   = lane & 15, kq = lane >> 4;

    for (int kk = 0; kk < K; kk += 64) {
#pragma unroll
        for (int i = 0; i < 4; ++i) {
            gload16(aSrc[i] + kk, As + (size_t)(i * 256 + w * 64) * 8);
            gload16(bSrc[i] + kk, Bs + (size_t)(i * 256 + w * 64) * 8);
        }
        __syncthreads();
#pragma unroll
        for (int s = 0; s < 2; ++s) {
            h8 af[4], bf[4];
#pragma unroll
            for (int m = 0; m < 4; ++m) {
                int row = wm + m * 16 + ra;
                af[m] = *reinterpret_cast<const h8*>(As + row * 64 + (((s * 4 + kq) ^ (row & 7)) << 3));
            }
#pragma unroll
            for (int n = 0; n < 4; ++n) {
                int row = wn + n * 16 + ra;
                bf[n] = *reinterpret_cast<const h8*>(Bs + row * 64 + (((s * 4 + kq) ^ (row & 7)) << 3));
            }
#pragma unroll
            for (int m = 0; m < 4; ++m)
#pragma unroll
                for (int n = 0; n < 4; ++n)
                    acc[m][n] = __builtin_amdgcn_mfma_f32_16x16x32_f16(af[m], bf[n], acc[m][n], 0, 0, 0);
        }
        __syncthreads();
    }
}

// ---------------------- shared down (+ fused routed-slot combine when COMB)
template<bool COMB>
__global__ __launch_bounds__(256) void down_shared_kernel(
    const _Float16* __restrict__ sh, const _Float16* __restrict__ shdown,
    const _Float16* __restrict__ slotout, float* __restrict__ out) {
    const int m0 = blockIdx.y * 128;
    const int n0 = blockIdx.x * 128;
    const int tid = threadIdx.x;
    const int sc = ((tid & 7) ^ ((tid >> 3) & 7)) << 3;
    const int r0 = tid >> 3;
    const _Float16* aSrc[4]; const _Float16* bSrc[4];
#pragma unroll
    for (int i = 0; i < 4; ++i) {
        aSrc[i] = sh + (size_t)(m0 + i * 32 + r0) * SIDIM + sc;
        bSrc[i] = shdown + (size_t)(n0 + i * 32 + r0) * SIDIM + sc;
    }
    f4 acc[4][4] = {};
    gemm128<SIDIM>(aSrc, bSrc, acc);

    const int w = tid >> 6, lane = tid & 63;
    const int wm = (w & 1) * 64, wn = (w >> 1) * 64;
    const int cq = lane >> 4, cc = lane & 15;
#pragma unroll
    for (int m = 0; m < 4; ++m)
#pragma unroll
    for (int r = 0; r < 4; ++r) {
        int orow = wm + m * 16 + cq * 4 + r;
        size_t trow = (size_t)(m0 + orow);
#pragma unroll
        for (int n = 0; n < 4; ++n) {
            int col = n0 + wn + n * 16 + cc;
            float v = acc[m][n][r];
            if (COMB) {
                const _Float16* sp = slotout + trow * TOPK * HDIM + col;
#pragma unroll
                for (int k = 0; k < TOPK; ++k)
                    v += (float)sp[(size_t)k * HDIM];
            }
            out[trow * HDIM + col] = v;
        }
    }
}

// ---------------------------------------------------------------------------
extern "C" void kernel_launch(void* const* d_in, const int* in_sizes, int n_in,
                              void* d_out, int out_size, void* d_ws, size_t ws_size,
                              hipStream_t stream) {
    const float* x     = (const float*)d_in[0];
    const float* gw    = (const float*)d_in[1];
    const float* bias  = (const float*)d_in[2];
    const float* wup   = (const float*)d_in[3];
    const float* wdown = (const float*)d_in[4];
    const float* sup   = (const float*)d_in[5];
    const float* sdown = (const float*)d_in[6];
    float* out = (float*)d_out;

    char* ws = (char*)d_ws;
    size_t off = 0;
    auto take = [&](size_t bytes) {
        char* p = ws + off;
        off = (off + bytes + 255) & ~(size_t)255;
        return p;
    };
    _Float16* xh      = (_Float16*)take((size_t)T_TOK * HDIM * 2);
    _Float16* whup    = (_Float16*)take((size_t)NEXP * IDIM * HDIM * 2);
    _Float16* whdown  = (_Float16*)take((size_t)NEXP * HDIM * IDIM * 2);
    _Float16* shupW   = (_Float16*)take((size_t)SIDIM * HDIM * 2);
    _Float16* shdownW = (_Float16*)take((size_t)HDIM * SIDIM * 2);
    _Float16* sh      = (_Float16*)take((size_t)T_TOK * SIDIM * 2);
    _Float16* hbuf    = (_Float16*)take((size_t)T_TOK * TOPK * IDIM * 2);
    int*   ids       = (int*)take((size_t)T_TOK * TOPK * 4);
    float* tw        = (float*)take((size_t)T_TOK * TOPK * 4);
    int*   tok_list  = (int*)take((size_t)NEXP * T_TOK * 4);
    float* wt_list   = (float*)take((size_t)NEXP * T_TOK * 4);
    int*   dest_list = (int*)take((size_t)NEXP * T_TOK * 4);
    int*   counts    = (int*)take(NEXP * 4);
    int*   offsets   = (int*)take((NEXP + 1) * 4);
    int*   tmapU     = (int*)take((1 + 2 * MAXTU) * 4);
    int*   tmapD     = (int*)take((1 + 2 * MAXTD) * 4);
    int*   done      = (int*)take(4);
    _Float16* slotout = (_Float16*)take((size_t)T_TOK * TOPK * HDIM * 2);
    const bool use_slot = off <= ws_size;

    hipMemsetAsync(done, 0, 4, stream);

    logits_select_kernel<<<T_TOK / 16, 256, 0, stream>>>(x, gw, bias, ids, tw);
    build_scan_kernel<<<NEXP, 64, 0, stream>>>(
        ids, tw, tok_list, wt_list, dest_list, counts, offsets, tmapU, tmapD, done);

    cvt_all_kernel<<<2048, 256, 0, stream>>>(
        x, xh, T_TOK * HDIM / 4,
        wup, whup, NEXP * IDIM * HDIM / 4,
        wdown, whdown, NEXP * HDIM * IDIM / 4,
        sup, shupW, SIDIM * HDIM / 4,
        sdown, shdownW, HDIM * SIDIM / 4);

    // unified up (routed + shared chunks): tiles x N-128-tiles
    up_kernel<<<dim3(MAXTU, 4), 256, 0, stream>>>(
        xh, whup, shupW, tok_list, wt_list, counts, offsets, tmapU, hbuf, sh);

    if (use_slot) {
        down_routed_kernel<true><<<dim3(MAXTD, HDIM / 128), 256, 0, stream>>>(
            hbuf, whdown, dest_list, counts, offsets, tmapD, slotout, out);
        down_shared_kernel<true><<<dim3(HDIM / 128, T_TOK / 128), 256, 0, stream>>>(
            sh, shdownW, slotout, out);
    } else {
        down_shared_kernel<false><<<dim3(HDIM / 128, T_TOK / 128), 256, 0, stream>>>(
            sh, shdownW, slotout, out);
        down_routed_kernel<false><<<dim3(MAXTD, HDIM / 128), 256, 0, stream>>>(
            hbuf, whdown, dest_list, counts, offsets, tmapD, slotout, out);
    }
}

// Round 15
// 306.469 us; speedup vs baseline: 1.0756x; 1.0756x over previous
//
#include <hip/hip_runtime.h>
#include <hip/hip_bf16.h>

// ---------------------------------------------------------------------------
// Nemotron-H MoE: T=4096 H=1024 E=32 (top-8, grouped 8x4) I=512, SI=2048.
// Round 15: revert to R13 (best measured, 306.6us). R14's 32x32-MFMA variant
// is structurally bank-conflicted (bank = chunk*4 mod 32 -> row drops out;
// 8 chunks for 32 lanes = inherent 4-way conflict); 16x16 stays <=2-way.
// Config: 256x128 single-buffered 2-phase gemm2p (2 blocks/CU), XCD swizzle,
// fused build+scan, separate fp64 router + cvt_all, fused combine epilogue.
// ---------------------------------------------------------------------------

typedef _Float16 h8 __attribute__((ext_vector_type(8)));
typedef _Float16 h4 __attribute__((ext_vector_type(4)));
typedef float f4 __attribute__((ext_vector_type(4)));

#define T_TOK 4096
#define HDIM  1024
#define NEXP  32
#define IDIM  512
#define SIDIM 2048
#define TOPK  8
#define MAXTU 224   // routed <=160 + shared 4*16; divisible by 8 (XCD swizzle)
#define MAXTD 160   // divisible by 8

// bijective XCD chunking (m204)
__device__ __forceinline__ int xcd_swz(int orig, int n) {
    int q = n >> 3, r = n & 7;
    int x = orig & 7, idx = orig >> 3;
    return (x < r ? x * (q + 1) : r * (q + 1) + (x - r) * q) + idx;
}

// async global->LDS, 16B per lane; LDS dest = wave-uniform base + lane*16
__device__ __forceinline__ void gload16(const void* g, void* l) {
    __builtin_amdgcn_global_load_lds(
        (const __attribute__((address_space(1))) void*)g,
        (__attribute__((address_space(3))) void*)l, 16, 0, 0);
}

// ------------------------------------------------ merged fp32->fp16 conversions
__global__ __launch_bounds__(256) void cvt_all_kernel(
    const float* __restrict__ sA, _Float16* __restrict__ dA, int nA,
    const float* __restrict__ sB, _Float16* __restrict__ dB, int nB,
    const float* __restrict__ sC, _Float16* __restrict__ dC, int nC,
    const float* __restrict__ sD, _Float16* __restrict__ dD, int nD,
    const float* __restrict__ sE, _Float16* __restrict__ dE, int nE) {
    const int total = nA + nB + nC + nD + nE;
    for (int gi = blockIdx.x * 256 + threadIdx.x; gi < total; gi += gridDim.x * 256) {
        const float* s; _Float16* d; int i = gi;
        if (i < nA) { s = sA; d = dA; }
        else { i -= nA;
        if (i < nB) { s = sB; d = dB; }
        else { i -= nB;
        if (i < nC) { s = sC; d = dC; }
        else { i -= nC;
        if (i < nD) { s = sD; d = dD; }
        else { i -= nD; s = sE; d = dE; } } } }
        float4 v = reinterpret_cast<const float4*>(s)[i];
        h4 h; h[0] = (_Float16)v.x; h[1] = (_Float16)v.y; h[2] = (_Float16)v.z; h[3] = (_Float16)v.w;
        reinterpret_cast<h4*>(d)[i] = h;
    }
}

// ------------------------------------------------ router: fp64 logits + select
__global__ __launch_bounds__(256) void logits_select_kernel(
    const float* __restrict__ x, const float* __restrict__ gw,
    const float* __restrict__ bias, int* __restrict__ topk_ids,
    float* __restrict__ topk_w) {
    const int t0  = blockIdx.x * 16;
    const int tid = threadIdx.x;
    __shared__ double xS[16][66];
    __shared__ double gS[32][65];
    __shared__ double sS[16][33];
    __shared__ double sfcS[16][33];
    const int e  = tid & 31;
    const int tg = tid >> 5;
    const int tA = tg * 2, tB = tg * 2 + 1;
    double acc0 = 0.0, acc1 = 0.0;

    for (int kc = 0; kc < HDIM; kc += 64) {
        {
            int r = tid >> 4, c0 = (tid & 15) * 4;
            float4 v = *reinterpret_cast<const float4*>(x + (size_t)(t0 + r) * HDIM + kc + c0);
            xS[r][c0]     = (double)v.x;
            xS[r][c0 + 1] = (double)v.y;
            xS[r][c0 + 2] = (double)v.z;
            xS[r][c0 + 3] = (double)v.w;
        }
        {
            int r = tid >> 3, c0 = (tid & 7) * 8;
            const float* gp = gw + (size_t)r * HDIM + kc + c0;
            float4 v0 = *reinterpret_cast<const float4*>(gp);
            float4 v1 = *reinterpret_cast<const float4*>(gp + 4);
            gS[r][c0]     = (double)v0.x;
            gS[r][c0 + 1] = (double)v0.y;
            gS[r][c0 + 2] = (double)v0.z;
            gS[r][c0 + 3] = (double)v0.w;
            gS[r][c0 + 4] = (double)v1.x;
            gS[r][c0 + 5] = (double)v1.y;
            gS[r][c0 + 6] = (double)v1.z;
            gS[r][c0 + 7] = (double)v1.w;
        }
        __syncthreads();
#pragma unroll
        for (int k = 0; k < 64; ++k) {
            double g = gS[e][k];
            acc0 = fma(g, xS[tA][k], acc0);
            acc1 = fma(g, xS[tB][k], acc1);
        }
        __syncthreads();
    }
    {
        double s0 = 1.0 / (1.0 + exp(-acc0));
        double s1 = 1.0 / (1.0 + exp(-acc1));
        double b = (double)bias[e];
        sS[tA][e] = s0;  sfcS[tA][e] = s0 + b;
        sS[tB][e] = s1;  sfcS[tB][e] = s1 + b;
    }
    __syncthreads();

    if (tid < 16) {
        const int t = t0 + tid;
        double gsc[8];
        for (int g = 0; g < 8; ++g) {
            double m1 = -1e300, m2 = -1e300;
            for (int j = 0; j < 4; ++j) {
                double v = sfcS[tid][g * 4 + j];
                if (v > m1) { m2 = m1; m1 = v; } else if (v > m2) { m2 = v; }
            }
            gsc[g] = m1 + m2;
        }
        bool gsel[8] = {};
        for (int r = 0; r < 4; ++r) {
            int best = 0; double bv = -1e300;
            for (int g = 0; g < 8; ++g)
                if (!gsel[g] && gsc[g] > bv) { bv = gsc[g]; best = g; }
            gsel[best] = true;
        }
        bool esel[32];
        for (int i2 = 0; i2 < 32; ++i2) esel[i2] = false;
        int ids[8]; double wsum = 0.0;
        for (int r = 0; r < 8; ++r) {
            int best = 0; double bv = -1e300;
            for (int e2 = 0; e2 < 32; ++e2)
                if (gsel[e2 >> 2] && !esel[e2] && sfcS[tid][e2] > bv) { bv = sfcS[tid][e2]; best = e2; }
            esel[best] = true;
            ids[r] = best;
            wsum += sS[tid][best];
        }
        for (int r = 0; r < 8; ++r) {
            topk_ids[t * TOPK + r] = ids[r];
            topk_w[t * TOPK + r] = (float)(sS[tid][ids[r]] / wsum * 2.5);
        }
    }
}

// --------------------------- build lists + scan (last-block does the scan)
__global__ void build_scan_kernel(const int* __restrict__ ids, const float* __restrict__ w,
                                  int* __restrict__ tok_list, float* __restrict__ wt_list,
                                  int* __restrict__ dest_list, int* __restrict__ counts,
                                  int* __restrict__ offsets, int* __restrict__ tmapU,
                                  int* __restrict__ tmapD, int* __restrict__ done) {
    const int e = blockIdx.x;
    const int lane = threadIdx.x;  // block of 64
    int base = 0;
    for (int t0 = 0; t0 < T_TOK; t0 += 64) {
        int t = t0 + lane;
        int found = -1;
#pragma unroll
        for (int k = 0; k < TOPK; ++k)
            if (ids[t * TOPK + k] == e) found = k;
        unsigned long long mask = __ballot(found >= 0);
        if (found >= 0) {
            int pos = base + __popcll(mask & ((1ull << lane) - 1ull));
            tok_list[e * T_TOK + pos]  = t;
            wt_list[e * T_TOK + pos]   = w[t * TOPK + found];
            dest_list[e * T_TOK + pos] = t * TOPK + found;
        }
        base += __popcll(mask);
    }
    if (lane == 0) counts[e] = base;
    __threadfence();
    if (lane == 0 && atomicAdd(done, 1) == NEXP - 1) {
        int run = 0, ntu = 0, ntd = 0;
        for (int ee = 0; ee < NEXP; ++ee) {
            offsets[ee] = run;
            int c = counts[ee];
            for (int m0 = 0; m0 < c; m0 += 256) {
                tmapU[1 + 2 * ntu] = ee; tmapU[2 + 2 * ntu] = m0; ++ntu;
                tmapD[1 + 2 * ntd] = ee; tmapD[2 + 2 * ntd] = m0; ++ntd;
            }
            run += c;
        }
        offsets[NEXP] = run;
        for (int c = 0; c < 4; ++c)
            for (int m0 = 0; m0 < T_TOK; m0 += 256) {
                tmapU[1 + 2 * ntu] = NEXP + c; tmapU[2 + 2 * ntu] = m0; ++ntu;
            }
        tmapU[0] = ntu;
        tmapD[0] = ntd;
    }
}

// ---------------------------------------------------------------------------
// gemm2p: 256x128 tile, BK=64, 256 threads (4 waves = 2M x 2N; per-wave
// output 128x64 = acc[8][4] of 16x16x32 frags). SINGLE-buffered LDS (48KB)
// -> 2 blocks/CU co-resident (reg-bound ~240/wave). Per K-tile:
// {stage 12 gload16; __syncthreads; 24 ds_read + 64 MFMA; __syncthreads}.
// Barrier drain hides under the co-resident block (m97/m114 mechanism).
// 16x16 frags keep the XOR-chunk LDS reads <=2-way (free); 32x32 is
// provably >=4-way in this layout (R14).
// ---------------------------------------------------------------------------
__device__ __forceinline__ void gemm2p(const _Float16* const (&aP)[8],
                                       const _Float16* const (&bP)[4],
                                       const int nt, f4 (&acc)[8][4]) {
    __shared__ __attribute__((aligned(16))) _Float16 As[256 * 64];
    __shared__ __attribute__((aligned(16))) _Float16 Bs[128 * 64];
    const int tid = threadIdx.x;
    const int w = tid >> 6, lane = tid & 63;
    const int wr = w >> 1, wc = w & 1;
    const int ra = lane & 15, kq = lane >> 4;
    const int ldsw = w * 512;                     // wave's 8-row chunk (halfs)
    const int arow = wr * 128 + ra;
    const int brow = wc * 64 + ra;
    const int ch0 = (kq ^ (ra & 7)) << 3;         // ks=0 swizzled chunk (halfs)
    const int ch1 = ((4 + kq) ^ (ra & 7)) << 3;   // ks=1

    for (int t = 0; t < nt; ++t) {
        const int ko = t * 64;
        // stage tile t (single buffer): A 8 sweeps of 32 rows, B 4 sweeps
#pragma unroll
        for (int s = 0; s < 8; ++s)
            gload16(aP[s] + ko, &As[s * 2048 + ldsw]);
#pragma unroll
        for (int s = 0; s < 4; ++s)
            gload16(bP[s] + ko, &Bs[s * 2048 + ldsw]);
        __syncthreads();   // compiler drains vmcnt+lgkm; co-block computes

        h8 bf0[4], bf1[4];
#pragma unroll
        for (int n = 0; n < 4; ++n) {
            bf0[n] = *reinterpret_cast<const h8*>(&Bs[(brow + n * 16) * 64 + ch0]);
            bf1[n] = *reinterpret_cast<const h8*>(&Bs[(brow + n * 16) * 64 + ch1]);
        }
        {
            h8 af[4];
#pragma unroll
            for (int m = 0; m < 4; ++m)
                af[m] = *reinterpret_cast<const h8*>(&As[(arow + m * 16) * 64 + ch0]);
            __builtin_amdgcn_s_setprio(1);
#pragma unroll
            for (int m = 0; m < 4; ++m)
#pragma unroll
                for (int n = 0; n < 4; ++n)
                    acc[m][n] = __builtin_amdgcn_mfma_f32_16x16x32_f16(af[m], bf0[n], acc[m][n], 0, 0, 0);
            __builtin_amdgcn_s_setprio(0);
        }
        {
            h8 af[4];
#pragma unroll
            for (int m = 0; m < 4; ++m)
                af[m] = *reinterpret_cast<const h8*>(&As[(arow + (m + 4) * 16) * 64 + ch0]);
            __builtin_amdgcn_s_setprio(1);
#pragma unroll
            for (int m = 0; m < 4; ++m)
#pragma unroll
                for (int n = 0; n < 4; ++n)
                    acc[m + 4][n] = __builtin_amdgcn_mfma_f32_16x16x32_f16(af[m], bf0[n], acc[m + 4][n], 0, 0, 0);
            __builtin_amdgcn_s_setprio(0);
        }
        {
            h8 af[4];
#pragma unroll
            for (int m = 0; m < 4; ++m)
                af[m] = *reinterpret_cast<const h8*>(&As[(arow + m * 16) * 64 + ch1]);
            __builtin_amdgcn_s_setprio(1);
#pragma unroll
            for (int m = 0; m < 4; ++m)
#pragma unroll
                for (int n = 0; n < 4; ++n)
                    acc[m][n] = __builtin_amdgcn_mfma_f32_16x16x32_f16(af[m], bf1[n], acc[m][n], 0, 0, 0);
            __builtin_amdgcn_s_setprio(0);
        }
        {
            h8 af[4];
#pragma unroll
            for (int m = 0; m < 4; ++m)
                af[m] = *reinterpret_cast<const h8*>(&As[(arow + (m + 4) * 16) * 64 + ch1]);
            __builtin_amdgcn_s_setprio(1);
#pragma unroll
            for (int m = 0; m < 4; ++m)
#pragma unroll
                for (int n = 0; n < 4; ++n)
                    acc[m + 4][n] = __builtin_amdgcn_mfma_f32_16x16x32_f16(af[m], bf1[n], acc[m + 4][n], 0, 0, 0);
            __builtin_amdgcn_s_setprio(0);
        }
        __syncthreads();   // all reads retired before next stage overwrites
    }
}

// ------------------------------ unified up: routed relu^2*g and shared relu^2
__global__ __launch_bounds__(256, 2) void up_kernel(
    const _Float16* __restrict__ xh, const _Float16* __restrict__ whup,
    const _Float16* __restrict__ shupW,
    const int* __restrict__ tok_list, const float* __restrict__ wt_list,
    const int* __restrict__ counts, const int* __restrict__ offsets,
    const int* __restrict__ tmap,
    _Float16* __restrict__ hbuf, _Float16* __restrict__ shb) {
    const int ntile = tmap[0];
    int ti = blockIdx.x;
    if (ti >= ntile) return;
    ti = xcd_swz(ti, ntile);
    const int e  = tmap[1 + 2 * ti];
    const int m0 = tmap[2 + 2 * ti];
    const int n0 = blockIdx.y * 128;
    const bool routed = e < NEXP;
    const int cnt = routed ? counts[e] : T_TOK;

    __shared__ int   tokS[256];
    __shared__ float wS[256];
    const int tid = threadIdx.x;
    {
        int row = m0 + tid;
        int cr = row < cnt ? row : cnt - 1;
        if (routed) {
            tokS[tid] = tok_list[e * T_TOK + cr];
            wS[tid]   = row < cnt ? wt_list[e * T_TOK + row] : 0.f;
        } else {
            tokS[tid] = cr;
            wS[tid]   = 1.f;
        }
    }
    __syncthreads();

    const int w = tid >> 6, lane = tid & 63;
    const int swz = ((lane & 7) ^ (lane >> 3)) << 3;
    const int rr = w * 8 + (lane >> 3);    // 0..31: row within each 32-row sweep
    const _Float16* bbase = routed ? (whup + (size_t)e * IDIM * HDIM)
                                   : (shupW + (size_t)(e - NEXP) * 512 * HDIM);
    const _Float16* aP[8]; const _Float16* bP[4];
#pragma unroll
    for (int s = 0; s < 8; ++s)
        aP[s] = xh + (size_t)tokS[s * 32 + rr] * HDIM + swz;
#pragma unroll
    for (int s = 0; s < 4; ++s)
        bP[s] = bbase + (size_t)(n0 + s * 32 + rr) * HDIM + swz;

    f4 acc[8][4] = {};
    gemm2p(aP, bP, HDIM / 64, acc);

    const int wr = w >> 1, wc = w & 1;
    const int kq = lane >> 4, ra = lane & 15;
    _Float16* obase; size_t ostr;
    if (routed) { obase = hbuf + (size_t)(offsets[e] + m0) * IDIM + n0; ostr = IDIM; }
    else        { obase = shb + (size_t)m0 * SIDIM + (size_t)(e - NEXP) * 512 + n0; ostr = SIDIM; }
#pragma unroll
    for (int m = 0; m < 8; ++m)
#pragma unroll
    for (int r = 0; r < 4; ++r) {
        int orow = wr * 128 + m * 16 + kq * 4 + r;
        if (m0 + orow < cnt) {
            float g = wS[orow];
#pragma unroll
            for (int n = 0; n < 4; ++n) {
                float v = fmaxf(acc[m][n][r], 0.f);
                obase[(size_t)orow * ostr + wc * 64 + n * 16 + ra] = (_Float16)(v * v * g);
            }
        }
    }
}

// ------------------------------------------------ routed down (2-phase core)
template<bool SLOT>
__global__ __launch_bounds__(256, 2) void down_routed_kernel(
    const _Float16* __restrict__ hbuf, const _Float16* __restrict__ whdown,
    const int* __restrict__ dest_list, const int* __restrict__ counts,
    const int* __restrict__ offsets, const int* __restrict__ tmap,
    _Float16* __restrict__ slotout, float* __restrict__ out) {
    const int ntile = tmap[0];
    int ti = blockIdx.x;
    if (ti >= ntile) return;
    ti = xcd_swz(ti, ntile);
    const int e   = tmap[1 + 2 * ti];
    const int m0  = tmap[2 + 2 * ti];
    const int cnt = counts[e];
    const int n0   = blockIdx.y * 128;
    const int eoff = offsets[e];

    __shared__ int dS[256];
    const int tid = threadIdx.x;
    {
        int row = m0 + tid;
        dS[tid] = dest_list[e * T_TOK + (row < cnt ? row : cnt - 1)];
    }
    __syncthreads();

    const int w = tid >> 6, lane = tid & 63;
    const int swz = ((lane & 7) ^ (lane >> 3)) << 3;
    const int rr = w * 8 + (lane >> 3);
    const _Float16* aP[8]; const _Float16* bP[4];
#pragma unroll
    for (int s = 0; s < 8; ++s) {
        int row = m0 + s * 32 + rr;
        int cr  = row < cnt ? row : cnt - 1;
        aP[s] = hbuf + (size_t)(eoff + cr) * IDIM + swz;
    }
#pragma unroll
    for (int s = 0; s < 4; ++s)
        bP[s] = whdown + ((size_t)e * HDIM + n0 + s * 32 + rr) * IDIM + swz;

    f4 acc[8][4] = {};
    gemm2p(aP, bP, IDIM / 64, acc);

    const int wr = w >> 1, wc = w & 1;
    const int kq = lane >> 4, ra = lane & 15;
#pragma unroll
    for (int m = 0; m < 8; ++m)
#pragma unroll
    for (int r = 0; r < 4; ++r) {
        int orow = wr * 128 + m * 16 + kq * 4 + r;
        if (m0 + orow < cnt) {
            int d = dS[orow];
            if (SLOT) {
                size_t rb = (size_t)d * HDIM + n0;
#pragma unroll
                for (int n = 0; n < 4; ++n)
                    slotout[rb + wc * 64 + n * 16 + ra] = (_Float16)acc[m][n][r];
            } else {
                size_t rb = (size_t)(d >> 3) * HDIM + n0;
#pragma unroll
                for (int n = 0; n < 4; ++n)
                    atomicAdd(&out[rb + wc * 64 + n * 16 + ra], acc[m][n][r]);
            }
        }
    }
}

// ---------------------------------------------------------------------------
// 128x128 2-phase GEMM (down_shared: 256-block grid + fused combine).
// ---------------------------------------------------------------------------
template<int K>
__device__ __forceinline__ void gemm128(const _Float16* const (&aSrc)[4],
                                        const _Float16* const (&bSrc)[4],
                                        f4 (&acc)[4][4]) {
    __shared__ __attribute__((aligned(16))) _Float16 As[128 * 64];
    __shared__ __attribute__((aligned(16))) _Float16 Bs[128 * 64];
    const int tid  = threadIdx.x;
    const int w    = tid >> 6, lane = tid & 63;
    const int wm   = (w & 1) * 64, wn = (w >> 1) * 64;
    const int ra   = lane & 15, kq = lane >> 4;

    for (int kk = 0; kk < K; kk += 64) {
#pragma unroll
        for (int i = 0; i < 4; ++i) {
            gload16(aSrc[i] + kk, As + (size_t)(i * 256 + w * 64) * 8);
            gload16(bSrc[i] + kk, Bs + (size_t)(i * 256 + w * 64) * 8);
        }
        __syncthreads();
#pragma unroll
        for (int s = 0; s < 2; ++s) {
            h8 af[4], bf[4];
#pragma unroll
            for (int m = 0; m < 4; ++m) {
                int row = wm + m * 16 + ra;
                af[m] = *reinterpret_cast<const h8*>(As + row * 64 + (((s * 4 + kq) ^ (row & 7)) << 3));
            }
#pragma unroll
            for (int n = 0; n < 4; ++n) {
                int row = wn + n * 16 + ra;
                bf[n] = *reinterpret_cast<const h8*>(Bs + row * 64 + (((s * 4 + kq) ^ (row & 7)) << 3));
            }
#pragma unroll
            for (int m = 0; m < 4; ++m)
#pragma unroll
                for (int n = 0; n < 4; ++n)
                    acc[m][n] = __builtin_amdgcn_mfma_f32_16x16x32_f16(af[m], bf[n], acc[m][n], 0, 0, 0);
        }
        __syncthreads();
    }
}

// ---------------------- shared down (+ fused routed-slot combine when COMB)
template<bool COMB>
__global__ __launch_bounds__(256) void down_shared_kernel(
    const _Float16* __restrict__ sh, const _Float16* __restrict__ shdown,
    const _Float16* __restrict__ slotout, float* __restrict__ out) {
    const int m0 = blockIdx.y * 128;
    const int n0 = blockIdx.x * 128;
    const int tid = threadIdx.x;
    const int sc = ((tid & 7) ^ ((tid >> 3) & 7)) << 3;
    const int r0 = tid >> 3;
    const _Float16* aSrc[4]; const _Float16* bSrc[4];
#pragma unroll
    for (int i = 0; i < 4; ++i) {
        aSrc[i] = sh + (size_t)(m0 + i * 32 + r0) * SIDIM + sc;
        bSrc[i] = shdown + (size_t)(n0 + i * 32 + r0) * SIDIM + sc;
    }
    f4 acc[4][4] = {};
    gemm128<SIDIM>(aSrc, bSrc, acc);

    const int w = tid >> 6, lane = tid & 63;
    const int wm = (w & 1) * 64, wn = (w >> 1) * 64;
    const int cq = lane >> 4, cc = lane & 15;
#pragma unroll
    for (int m = 0; m < 4; ++m)
#pragma unroll
    for (int r = 0; r < 4; ++r) {
        int orow = wm + m * 16 + cq * 4 + r;
        size_t trow = (size_t)(m0 + orow);
#pragma unroll
        for (int n = 0; n < 4; ++n) {
            int col = n0 + wn + n * 16 + cc;
            float v = acc[m][n][r];
            if (COMB) {
                const _Float16* sp = slotout + trow * TOPK * HDIM + col;
#pragma unroll
                for (int k = 0; k < TOPK; ++k)
                    v += (float)sp[(size_t)k * HDIM];
            }
            out[trow * HDIM + col] = v;
        }
    }
}

// ---------------------------------------------------------------------------
extern "C" void kernel_launch(void* const* d_in, const int* in_sizes, int n_in,
                              void* d_out, int out_size, void* d_ws, size_t ws_size,
                              hipStream_t stream) {
    const float* x     = (const float*)d_in[0];
    const float* gw    = (const float*)d_in[1];
    const float* bias  = (const float*)d_in[2];
    const float* wup   = (const float*)d_in[3];
    const float* wdown = (const float*)d_in[4];
    const float* sup   = (const float*)d_in[5];
    const float* sdown = (const float*)d_in[6];
    float* out = (float*)d_out;

    char* ws = (char*)d_ws;
    size_t off = 0;
    auto take = [&](size_t bytes) {
        char* p = ws + off;
        off = (off + bytes + 255) & ~(size_t)255;
        return p;
    };
    _Float16* xh      = (_Float16*)take((size_t)T_TOK * HDIM * 2);
    _Float16* whup    = (_Float16*)take((size_t)NEXP * IDIM * HDIM * 2);
    _Float16* whdown  = (_Float16*)take((size_t)NEXP * HDIM * IDIM * 2);
    _Float16* shupW   = (_Float16*)take((size_t)SIDIM * HDIM * 2);
    _Float16* shdownW = (_Float16*)take((size_t)HDIM * SIDIM * 2);
    _Float16* sh      = (_Float16*)take((size_t)T_TOK * SIDIM * 2);
    _Float16* hbuf    = (_Float16*)take((size_t)T_TOK * TOPK * IDIM * 2);
    int*   ids       = (int*)take((size_t)T_TOK * TOPK * 4);
    float* tw        = (float*)take((size_t)T_TOK * TOPK * 4);
    int*   tok_list  = (int*)take((size_t)NEXP * T_TOK * 4);
    float* wt_list   = (float*)take((size_t)NEXP * T_TOK * 4);
    int*   dest_list = (int*)take((size_t)NEXP * T_TOK * 4);
    int*   counts    = (int*)take(NEXP * 4);
    int*   offsets   = (int*)take((NEXP + 1) * 4);
    int*   tmapU     = (int*)take((1 + 2 * MAXTU) * 4);
    int*   tmapD     = (int*)take((1 + 2 * MAXTD) * 4);
    int*   done      = (int*)take(4);
    _Float16* slotout = (_Float16*)take((size_t)T_TOK * TOPK * HDIM * 2);
    const bool use_slot = off <= ws_size;

    hipMemsetAsync(done, 0, 4, stream);

    logits_select_kernel<<<T_TOK / 16, 256, 0, stream>>>(x, gw, bias, ids, tw);
    build_scan_kernel<<<NEXP, 64, 0, stream>>>(
        ids, tw, tok_list, wt_list, dest_list, counts, offsets, tmapU, tmapD, done);

    cvt_all_kernel<<<2048, 256, 0, stream>>>(
        x, xh, T_TOK * HDIM / 4,
        wup, whup, NEXP * IDIM * HDIM / 4,
        wdown, whdown, NEXP * HDIM * IDIM / 4,
        sup, shupW, SIDIM * HDIM / 4,
        sdown, shdownW, HDIM * SIDIM / 4);

    // unified up (routed + shared chunks): tiles x N-128-tiles
    up_kernel<<<dim3(MAXTU, 4), 256, 0, stream>>>(
        xh, whup, shupW, tok_list, wt_list, counts, offsets, tmapU, hbuf, sh);

    if (use_slot) {
        down_routed_kernel<true><<<dim3(MAXTD, HDIM / 128), 256, 0, stream>>>(
            hbuf, whdown, dest_list, counts, offsets, tmapD, slotout, out);
        down_shared_kernel<true><<<dim3(HDIM / 128, T_TOK / 128), 256, 0, stream>>>(
            sh, shdownW, slotout, out);
    } else {
        down_shared_kernel<false><<<dim3(HDIM / 128, T_TOK / 128), 256, 0, stream>>>(
            sh, shdownW, slotout, out);
        down_routed_kernel<false><<<dim3(MAXTD, HDIM / 128), 256, 0, stream>>>(
            hbuf, whdown, dest_list, counts, offsets, tmapD, slotout, out);
    }
}